// Round 4
// baseline (621.927 us; speedup 1.0000x reference)
//
#include <hip/hip_runtime.h>

typedef _Float16 half8 __attribute__((ext_vector_type(8)));
typedef float floatx4 __attribute__((ext_vector_type(4)));

#define T_STEPS 256
#define BB      16
#define NTH     512
#define NBLK    64

// ws layout in halves
#define WHH0_H  0
#define WIH1_H  65536
#define WHH1_H  131072
#define WIH0_H  196608

__device__ __forceinline__ float sig_(float z)  { return __builtin_amdgcn_rcpf(1.f + __expf(-z)); }
__device__ __forceinline__ float tanh_(float z) { return 1.f - 2.f * __builtin_amdgcn_rcpf(1.f + __expf(2.f * z)); }

// Build fp16 MFMA B-fragment arrays.
// Frag index: ((wv*4+gi)*4+ks)*64 + lane ; lane holds W[gi*128+wv*16+(l&15)][ks*32+(l>>4)*8 + j]
__global__ __launch_bounds__(256) void prep_weights(
    const float* __restrict__ w_ih0, const float* __restrict__ w_hh0,
    const float* __restrict__ w_ih1, const float* __restrict__ w_hh1,
    _Float16* __restrict__ wf)
{
    const int idx = blockIdx.x * 256 + threadIdx.x;   // 0..8191
    const int l  = idx & 63;
    const int ks = (idx >> 6) & 3;
    const int gi = (idx >> 8) & 3;
    const int wv = (idx >> 10) & 7;
    const int row = gi * 128 + wv * 16 + (l & 15);
    const int kb  = ks * 32 + (l >> 4) * 8;
#pragma unroll
    for (int j = 0; j < 8; ++j) {
        wf[WHH0_H + idx * 8 + j] = (_Float16)w_hh0[row * 128 + kb + j];
        wf[WIH1_H + idx * 8 + j] = (_Float16)w_ih1[row * 128 + kb + j];
        wf[WHH1_H + idx * 8 + j] = (_Float16)w_hh1[row * 128 + kb + j];
    }
    if (ks == 0) {
        // x-frag convention: lk=0 -> W[0..7]; lk=1 -> 0,0,W[8..13]; lk>=2 -> 0
        const int lk = l >> 4;
        const int oi = ((wv * 4 + gi) * 64 + l) * 8;
#pragma unroll
        for (int j = 0; j < 8; ++j) {
            float v = 0.f;
            if (lk == 0)                v = w_ih0[row * 14 + j];
            else if (lk == 1 && j >= 2) v = w_ih0[row * 14 + 6 + j];
            wf[WIH0_H + oi + j] = (_Float16)v;
        }
    }
}

// LDS-only barrier: drains ds ops, leaves global loads in flight (no global
// stores or cross-block comms inside the loop -> vmcnt drain not needed).
#define BARRIER() do {                                          \
    asm volatile("s_waitcnt lgkmcnt(0)" ::: "memory");          \
    __builtin_amdgcn_s_barrier();                               \
    __builtin_amdgcn_sched_barrier(0);                          \
} while (0)

#define READFRAG(DSTARR, SRC) do {                                              \
    _Pragma("unroll")                                                           \
    for (int ks = 0; ks < 4; ++ks) {                                            \
        const int off = lrow * 256 + ((ks * 64 + lk * 16) ^ ((lrow & 7) << 4)); \
        DSTARR[ks] = *(const half8*)((const char*)(SRC) + off);                 \
    }                                                                           \
} while (0)

#define ACTWRITE(ACC, CST, DST) do {                                            \
    _Pragma("unroll")                                                           \
    for (int r = 0; r < 4; ++r) {                                               \
        const float ig = sig_(ACC[0][r]);                                       \
        const float fg = sig_(ACC[1][r]);                                       \
        const float gg = tanh_(ACC[2][r]);                                      \
        const float og = sig_(ACC[3][r]);                                       \
        CST[r] = fg * CST[r] + ig * gg;                                         \
        const float hv = og * tanh_(CST[r]);                                    \
        const int b = lk * 4 + r;                                               \
        *(_Float16*)((DST) + b * 256 + (((u * 2)) ^ ((b & 7) << 4))) = (_Float16)hv; \
    }                                                                           \
} while (0)

__global__ __launch_bounds__(NTH, 2) void lstm2_fused3(
    const float* __restrict__ x, const _Float16* __restrict__ wf,
    const float* __restrict__ b_ih0, const float* __restrict__ b_hh0,
    const float* __restrict__ b_ih1, const float* __restrict__ b_hh1,
    const float* __restrict__ w_lin, const float* __restrict__ b_lin,
    float* __restrict__ out)
{
    __shared__ __align__(16) _Float16 whh0_lds[65536];     // 128 KB, frag-ordered
    __shared__ __align__(16) _Float16 h1s[3][BB * 128];    // 3 x 4 KB, XOR-swizzled
    __shared__ __align__(16) _Float16 h2s[3][BB * 128];    // 3 x 4 KB

    const int tid  = threadIdx.x;
    const int l    = tid & 63;
    const int wv   = tid >> 6;
    const int lrow = l & 15;
    const int lk   = l >> 4;
    const int b0   = blockIdx.x * BB;
    const int u    = wv * 16 + lrow;

    // stage whh0 frags to LDS; zero h slots
    {
        const floatx4* src = (const floatx4*)(wf + WHH0_H);
        floatx4* dst = (floatx4*)whh0_lds;
        for (int i = tid; i < 8192; i += NTH) dst[i] = src[i];
    }
    for (int i = tid; i < 3072; i += NTH) {
        ((unsigned*)h1s)[i] = 0u;
        ((unsigned*)h2s)[i] = 0u;
    }

    // resident weight fragments (budgeted by __launch_bounds__(512,2))
    const half8* wsf = (const half8*)wf;
    half8 wih1f[16], whh1f[16], wih0f[4];
#pragma unroll
    for (int gi = 0; gi < 4; ++gi) {
#pragma unroll
        for (int ks = 0; ks < 4; ++ks) {
            const int idx = ((wv * 4 + gi) * 4 + ks) * 64 + l;
            wih1f[gi * 4 + ks] = wsf[WIH1_H / 8 + idx];
            whh1f[gi * 4 + ks] = wsf[WHH1_H / 8 + idx];
        }
        wih0f[gi] = wsf[WIH0_H / 8 + (wv * 4 + gi) * 64 + l];
    }
    float bias1[4], bias2[4];
#pragma unroll
    for (int gi = 0; gi < 4; ++gi) {
        const int col = gi * 128 + wv * 16 + lrow;
        bias1[gi] = b_ih0[col] + b_hh0[col];
        bias2[gi] = b_ih1[col] + b_hh1[col];
    }
    float c1[4] = {0.f, 0.f, 0.f, 0.f}, c2[4] = {0.f, 0.f, 0.f, 0.f};

    // x prefetch (stays in flight across raw barriers)
    const int coff = (lk == 1) ? 6 : 0;
    const float* xp = x + (size_t)(b0 + lrow) * (T_STEPS * 14) + coff;
    float xr[8];
#pragma unroll
    for (int j = 0; j < 8; ++j) xr[j] = xp[j];

    const char* wbase = (const char*)whh0_lds + (wv * 1024 + l) * 16;

    BARRIER();   // whh0 staged + h zeroed visible

    int sa = 0, sb = 1, scc = 2;   // sa=t%3 (h1 write), sb=(t+1)%3, scc=(t+2)%3
    for (int t = 0; t < T_STEPS; ++t) {
        half8 xh;
#pragma unroll
        for (int j = 0; j < 8; ++j) xh[j] = (_Float16)xr[j];
        if (t + 1 < T_STEPS) {
#pragma unroll
            for (int j = 0; j < 8; ++j) xr[j] = xp[(t + 1) * 14 + j];
        }

        // h1(t-1) A-frags -- shared by layer-1 hh and layer-2 ih
        half8 h1p[4];
        READFRAG(h1p, h1s[scc]);

        // layer-1 gates
        floatx4 acc1[4];
#pragma unroll
        for (int gi = 0; gi < 4; ++gi) {
            acc1[gi] = (floatx4){bias1[gi], bias1[gi], bias1[gi], bias1[gi]};
            acc1[gi] = __builtin_amdgcn_mfma_f32_16x16x32_f16(xh, wih0f[gi], acc1[gi], 0, 0, 0);
#pragma unroll
            for (int ks = 0; ks < 4; ++ks) {
                const half8 wb = *(const half8*)(wbase + (gi * 4 + ks) * 1024);
                acc1[gi] = __builtin_amdgcn_mfma_f32_16x16x32_f16(h1p[ks], wb, acc1[gi], 0, 0, 0);
            }
        }

        // layer-2 (skewed): h2(t-1) = f(h2(t-2), h1(t-1))
        if (t > 0) {
            half8 h2p[4];
            READFRAG(h2p, h2s[sb]);
            floatx4 acc2[4];
#pragma unroll
            for (int gi = 0; gi < 4; ++gi) {
                acc2[gi] = (floatx4){bias2[gi], bias2[gi], bias2[gi], bias2[gi]};
#pragma unroll
                for (int ks = 0; ks < 4; ++ks) {
                    acc2[gi] = __builtin_amdgcn_mfma_f32_16x16x32_f16(h2p[ks], whh1f[gi * 4 + ks], acc2[gi], 0, 0, 0);
                    acc2[gi] = __builtin_amdgcn_mfma_f32_16x16x32_f16(h1p[ks], wih1f[gi * 4 + ks], acc2[gi], 0, 0, 0);
                }
            }
            ACTWRITE(acc2, c2, (char*)h2s[scc]);
        }

        ACTWRITE(acc1, c1, (char*)h1s[sa]);

        BARRIER();
        const int tmp = sa; sa = sb; sb = scc; scc = tmp;
    }

    // tail: h2(255) = f(h2(254), h1(255));  (sa,sb,scc) = (1,2,0) here
    {
        half8 h1p[4], h2p[4];
        READFRAG(h1p, h1s[scc]);
        READFRAG(h2p, h2s[sb]);
        floatx4 acc2[4];
#pragma unroll
        for (int gi = 0; gi < 4; ++gi) {
            acc2[gi] = (floatx4){bias2[gi], bias2[gi], bias2[gi], bias2[gi]};
#pragma unroll
            for (int ks = 0; ks < 4; ++ks) {
                acc2[gi] = __builtin_amdgcn_mfma_f32_16x16x32_f16(h2p[ks], whh1f[gi * 4 + ks], acc2[gi], 0, 0, 0);
                acc2[gi] = __builtin_amdgcn_mfma_f32_16x16x32_f16(h1p[ks], wih1f[gi * 4 + ks], acc2[gi], 0, 0, 0);
            }
        }
        ACTWRITE(acc2, c2, (char*)h2s[scc]);
        BARRIER();
    }

    // epilogue: out[b] = h2(255)[b] . w_lin + b_lin ; h2(255) in h2s[0]
    if (tid < 64) {
        const char* hb = (const char*)h2s[0];
        const int bb = tid & 15, q = tid >> 4;
        float acc = 0.f;
#pragma unroll
        for (int j5 = 0; j5 < 32; ++j5) {
            const int j = q * 32 + j5;
            acc += w_lin[j] * (float)(*(const _Float16*)(hb + bb * 256 + ((j * 2) ^ ((bb & 7) << 4))));
        }
        acc += __shfl_xor(acc, 16, 64);
        acc += __shfl_xor(acc, 32, 64);
        if (q == 0) out[b0 + bb] = acc + b_lin[0];
    }
}

extern "C" void kernel_launch(void* const* d_in, const int* in_sizes, int n_in,
                              void* d_out, int out_size, void* d_ws, size_t ws_size,
                              hipStream_t stream) {
    (void)in_sizes; (void)n_in; (void)ws_size; (void)out_size;
    const float* x     = (const float*)d_in[0];
    const float* w_ih0 = (const float*)d_in[1];
    const float* w_hh0 = (const float*)d_in[2];
    const float* b_ih0 = (const float*)d_in[3];
    const float* b_hh0 = (const float*)d_in[4];
    const float* w_ih1 = (const float*)d_in[5];
    const float* w_hh1 = (const float*)d_in[6];
    const float* b_ih1 = (const float*)d_in[7];
    const float* b_hh1 = (const float*)d_in[8];
    const float* w_lin = (const float*)d_in[9];
    const float* b_lin = (const float*)d_in[10];
    float* out = (float*)d_out;

    hipLaunchKernelGGL(prep_weights, dim3(32), dim3(256), 0, stream,
                       w_ih0, w_hh0, w_ih1, w_hh1, (_Float16*)d_ws);
    hipLaunchKernelGGL(lstm2_fused3, dim3(NBLK), dim3(NTH), 0, stream,
                       x, (const _Float16*)d_ws, b_ih0, b_hh0, b_ih1, b_hh1,
                       w_lin, b_lin, out);
}